// Round 7
// baseline (174.952 us; speedup 1.0000x reference)
//
#include <hip/hip_runtime.h>
#include <math.h>

// Problem constants
#define NN 512
#define DD 512
#define NPAIRS 130816            // 512*511/2
#define TYPES_OFF 0              // [P,10] floats
#define ARGMAX_OFF 1308160      // [P] floats
#define STRENGTH_OFF 1438976    // [P] floats

// ws layout (byte offsets):
//   ca_d  double[512][512] @ 0         (cb1 folded + F@cw1[:D], fp64)
//   cb_d  double[512][512] @ 2097152   (F@cw1[D:], fp64)
//   sa_f  float [512][256] @ 4194304   (sb1 folded + F@sw1[:D])
//   sb_f  float [512][256] @ 4718592   (F@sw1[D:])
//   cw2d  double[512][10]  @ 5242880
// total 5,283,840 bytes

struct StageC { float4 a0, a1, b0, b1, b2, b3; };

__device__ __forceinline__ void fma64_step(const StageC& s, double acc[2][4]) {
    const float av[2][4] = {{s.a0.x,s.a0.y,s.a0.z,s.a0.w},{s.a1.x,s.a1.y,s.a1.z,s.a1.w}};
    const float bv[4][4] = {{s.b0.x,s.b0.y,s.b0.z,s.b0.w},{s.b1.x,s.b1.y,s.b1.z,s.b1.w},
                            {s.b2.x,s.b2.y,s.b2.z,s.b2.w},{s.b3.x,s.b3.y,s.b3.z,s.b3.w}};
    #pragma unroll
    for (int kk = 0; kk < 4; ++kk) {
        double ad0 = (double)av[0][kk], ad1 = (double)av[1][kk];
        #pragma unroll
        for (int c = 0; c < 4; ++c) {
            double bd = (double)bv[kk][c];
            acc[0][c] = fma(ad0, bd, acc[0][c]);
            acc[1][c] = fma(ad1, bd, acc[1][c]);
        }
    }
}

__device__ __forceinline__ void fma32_step(const StageC& s, float acc[2][4]) {
    const float av[2][4] = {{s.a0.x,s.a0.y,s.a0.z,s.a0.w},{s.a1.x,s.a1.y,s.a1.z,s.a1.w}};
    const float bv[4][4] = {{s.b0.x,s.b0.y,s.b0.z,s.b0.w},{s.b1.x,s.b1.y,s.b1.z,s.b1.w},
                            {s.b2.x,s.b2.y,s.b2.z,s.b2.w},{s.b3.x,s.b3.y,s.b3.z,s.b3.w}};
    #pragma unroll
    for (int kk = 0; kk < 4; ++kk) {
        #pragma unroll
        for (int c = 0; c < 4; ++c) {
            acc[0][c] = fmaf(av[0][kk], bv[kk][c], acc[0][c]);
            acc[1][c] = fmaf(av[1][kk], bv[kk][c], acc[1][c]);
        }
    }
}

// Barrier-free, LDS-free, atomic-free, NO-K-split projection GEMM.
// Wave = 8m x 64n tile, thread = 2m x 4n, full K=512, depth-2 software pipeline.
// blocks [0,256):   fp64 classifier (1024 waves)
// blocks [256,384): fp32 strength   (512 waves)
// blocks [384,404): cw2 -> fp64 convert
__global__ __launch_bounds__(256, 2) void proj_kernel(
    const float* __restrict__ F, const float* __restrict__ cw1,
    const float* __restrict__ sw1,
    const float* __restrict__ cb1, const float* __restrict__ sb1,
    const float* __restrict__ cw2,
    double* __restrict__ ca_d, double* __restrict__ cb_d,
    float* __restrict__ sa_f, float* __restrict__ sb_f,
    double* __restrict__ cw2d)
{
    const int t = threadIdx.x;
    const int b = blockIdx.x;
    if (b >= 384) {                        // cw2 convert tail
        int idx = (b - 384) * 256 + t;
        if (idx < 5120) cw2d[idx] = (double)cw2[idx];
        return;
    }
    const int lane = t & 63;
    const int mg = lane >> 4;              // 0..3  (2-row group)
    const int nq = lane & 15;              // 0..15 (4-col group)

    if (b < 256) {
        // ---------------- fp64 classifier: out 512x1024 ----------------
        const int wid = b * 4 + (t >> 6);  // 0..1023
        const int mt = wid >> 4, nt = wid & 15;
        const int m0 = mt * 8, n = nt * 64;
        const float* W   = (n < 512) ? cw1 : cw1 + 262144;
        const int n0     = (n < 512) ? n : n - 512;
        double* outp     = (n < 512) ? ca_d : cb_d;
        const bool addb  = (n < 512);

        const int row0 = m0 + mg * 2;
        const int col0 = n0 + nq * 4;
        const float* pa0 = F + row0 * 512;
        const float* pa1 = pa0 + 512;
        const float* pb  = W + col0;

        double acc[2][4];
        #pragma unroll
        for (int r = 0; r < 2; ++r)
            #pragma unroll
            for (int c = 0; c < 4; ++c) acc[r][c] = 0.0;

        #define LDC(s) StageC{ *(const float4*)(pa0 + 4*(s)), *(const float4*)(pa1 + 4*(s)), \
            *(const float4*)(pb + (4*(s)+0)*512), *(const float4*)(pb + (4*(s)+1)*512), \
            *(const float4*)(pb + (4*(s)+2)*512), *(const float4*)(pb + (4*(s)+3)*512) }

        StageC c0 = LDC(0), c1 = LDC(1);
        for (int s = 0; s < 126; s += 2) {   // 63 iters; loads run 2 steps ahead
            StageC p0 = LDC(s + 2);
            StageC p1 = LDC(s + 3);
            fma64_step(c0, acc);
            fma64_step(c1, acc);
            c0 = p0; c1 = p1;
        }
        fma64_step(c0, acc);
        fma64_step(c1, acc);
        #undef LDC

        #pragma unroll
        for (int r = 0; r < 2; ++r) {
            double v[4];
            #pragma unroll
            for (int c = 0; c < 4; ++c) {
                v[c] = acc[r][c];
                if (addb) v[c] += (double)cb1[col0 + c];
            }
            double* dst = outp + (row0 + r) * 512 + col0;
            *(double2*)(dst + 0) = make_double2(v[0], v[1]);
            *(double2*)(dst + 2) = make_double2(v[2], v[3]);
        }
    } else {
        // ---------------- fp32 strength: out 512x512 ----------------
        const int wid = (b - 256) * 4 + (t >> 6);  // 0..511
        const int mt = wid >> 3, nt = wid & 7;
        const int m0 = mt * 8, n = nt * 64;
        const float* W  = (n < 256) ? sw1 : sw1 + 131072;
        const int n0    = (n < 256) ? n : n - 256;
        float* outp     = (n < 256) ? sa_f : sb_f;
        const bool addb = (n < 256);

        const int row0 = m0 + mg * 2;
        const int col0 = n0 + nq * 4;
        const float* pa0 = F + row0 * 512;
        const float* pa1 = pa0 + 512;
        const float* pb  = W + col0;

        float acc[2][4];
        #pragma unroll
        for (int r = 0; r < 2; ++r)
            #pragma unroll
            for (int c = 0; c < 4; ++c) acc[r][c] = 0.f;

        #define LDS4(s) StageC{ *(const float4*)(pa0 + 4*(s)), *(const float4*)(pa1 + 4*(s)), \
            *(const float4*)(pb + (4*(s)+0)*256), *(const float4*)(pb + (4*(s)+1)*256), \
            *(const float4*)(pb + (4*(s)+2)*256), *(const float4*)(pb + (4*(s)+3)*256) }

        StageC c0 = LDS4(0), c1 = LDS4(1);
        for (int s = 0; s < 126; s += 2) {
            StageC p0 = LDS4(s + 2);
            StageC p1 = LDS4(s + 3);
            fma32_step(c0, acc);
            fma32_step(c1, acc);
            c0 = p0; c1 = p1;
        }
        fma32_step(c0, acc);
        fma32_step(c1, acc);
        #undef LDS4

        #pragma unroll
        for (int r = 0; r < 2; ++r) {
            float4 v = make_float4(acc[r][0], acc[r][1], acc[r][2], acc[r][3]);
            if (addb) {
                v.x += sb1[col0 + 0]; v.y += sb1[col0 + 1];
                v.z += sb1[col0 + 2]; v.w += sb1[col0 + 3];
            }
            *(float4*)(outp + (row0 + r) * 256 + col0) = v;
        }
    }
}

// Pair phase: block = 8x8 pair tile, 4 waves = 4 K-quarters, LDS combine.
// Grid: 2080 triangular tiles. Register-prefetch of next chunk overlaps compute.
// NOTE: inner loops MUST stay scalar-read + partial-unroll (R3 form). Full unroll
// or wider per-iter weight footprints -> VGPR explosion -> lg[] spills to
// scratch (R2: 175 MB, R4: 149 MB WRITE_SIZE). Weights JIT, 10 at a time.
__global__ __launch_bounds__(256, 4) void pair_kernel(
    const double* __restrict__ ca_d, const double* __restrict__ cb_d,
    const float* __restrict__ sa_f, const float* __restrict__ sb_f,
    const double* __restrict__ cw2d, const float* __restrict__ cb2,
    const float* __restrict__ sw2, const float* __restrict__ sb2,
    float* __restrict__ out)
{
    // triangular tile decode: S(bi) = bi*(129-bi)/2
    const int b = blockIdx.x;
    int bi = (int)floorf((129.0f - sqrtf(16641.0f - 8.0f * (float)b)) * 0.5f);
    while ((bi + 1) * (129 - (bi + 1)) / 2 <= b) ++bi;
    while (bi * (129 - bi) / 2 > b) --bi;
    const int bj = bi + (b - bi * (129 - bi) / 2);
    const int i0 = bi * 8, j0 = bj * 8;

    const int t = threadIdx.x;
    const int q  = t >> 6;                               // K-quarter = wave id
    const int qu = __builtin_amdgcn_readfirstlane(q);    // wave-uniform -> s_load bases
    const int l = t & 63;
    const int pi = l >> 3, pj = l & 7;
    const int i = i0 + pi, j = j0 + pj;

    __shared__ double smem_d[2176];                 // 17408 B
    double* sA  = smem_d;                           // [4*8][34]
    double* sB  = smem_d + 1088;
    float*  sSa = (float*)smem_d;                   // [4*8][68]
    float*  sSb = (float*)smem_d + 2176;
    double* lgbuf = smem_d;                         // [3][64][10]
    float*  stbuf = (float*)(smem_d + 1920);        // [3][64]

    // staging decomposition of idx = u*256 + t (u = 0..3):
    //   kq = t&15, row = (t>>4)&7  (invariant in u)
    //   qq(u) = ((t>>7) + 2u) & 3,  arr(u) = u>>1
    const int kq  = t & 15;
    const int row = (t >> 4) & 7;
    const int qq0 = (t >> 7) & 3;          // 0 or 1

    // ---------------- strength (fp32), K=64 per quarter ----------------
    #pragma unroll
    for (int u = 0; u < 4; ++u) {
        int qqu = (qq0 + 2 * u) & 3;
        int arr = u >> 1;
        const float* src = arr ? (sb_f + (j0 + row) * 256) : (sa_f + (i0 + row) * 256);
        float4 v = *(const float4*)(src + qqu * 64 + kq * 4);
        float* dst = (arr ? sSb : sSa) + (qqu * 8 + row) * 68 + kq * 4;
        *(float4*)dst = v;
    }
    __syncthreads();

    // prefetch classifier chunk 0 (overlaps strength compute)
    const double* pfbase[4];
    #pragma unroll
    for (int u = 0; u < 4; ++u) {
        int qqu = (qq0 + 2 * u) & 3;
        int arr = u >> 1;
        pfbase[u] = (arr ? (cb_d + (j0 + row) * 512) : (ca_d + (i0 + row) * 512))
                    + qqu * 128 + kq * 2;
    }
    double2 pf[4];
    #pragma unroll
    for (int u = 0; u < 4; ++u) pf[u] = *(const double2*)(pfbase[u]);

    float accs = 0.f;
    {
        const float* sw2q = sw2 + qu * 64;
        const float* ra = sSa + (q * 8 + pi) * 68;
        const float* rb = sSb + (q * 8 + pj) * 68;
        #pragma unroll 16
        for (int kk = 0; kk < 64; ++kk) {
            float h = fmaxf(ra[kk] + rb[kk], 0.f);
            accs = fmaf(h, sw2q[kk], accs);
        }
    }

    // ---------------- classifier (fp64), K=128 per quarter ----------------
    double lg[10];
    #pragma unroll
    for (int c = 0; c < 10; ++c) lg[c] = 0.0;
    const double* wq = cw2d + qu * 1280;

    for (int c4 = 0; c4 < 4; ++c4) {
        __syncthreads();   // prior reads of sA/sB (or sSa/sSb) done
        #pragma unroll
        for (int u = 0; u < 4; ++u) {
            int qqu = (qq0 + 2 * u) & 3;
            int arr = u >> 1;
            double* dst = (arr ? sB : sA) + (qqu * 8 + row) * 34 + kq * 2;
            *(double2*)dst = pf[u];
        }
        __syncthreads();
        if (c4 < 3) {      // prefetch next chunk; latency overlaps compute below
            #pragma unroll
            for (int u = 0; u < 4; ++u)
                pf[u] = *(const double2*)(pfbase[u] + (c4 + 1) * 32);
        }
        const double* ra = sA + (q * 8 + pi) * 34;
        const double* rb = sB + (q * 8 + pj) * 34;
        const double* wc = wq + c4 * 320;
        #pragma unroll 8
        for (int kk = 0; kk < 32; ++kk) {
            double h = fmax(ra[kk] + rb[kk], 0.0);
            const double* w = wc + kk * 10;
            #pragma unroll
            for (int c = 0; c < 10; ++c) lg[c] = fma(h, w[c], lg[c]);
        }
    }

    // ---------------- combine via LDS ----------------
    __syncthreads();
    if (q > 0) {
        double* dst = lgbuf + ((q - 1) * 64 + l) * 10;
        #pragma unroll
        for (int c = 0; c < 10; ++c) dst[c] = lg[c];
        stbuf[(q - 1) * 64 + l] = accs;
    }
    __syncthreads();
    if (q == 0) {
        #pragma unroll
        for (int w = 0; w < 3; ++w) {
            const double* srcb = lgbuf + (w * 64 + l) * 10;
            #pragma unroll
            for (int c = 0; c < 10; ++c) lg[c] += srcb[c];
        }
        float st = accs + stbuf[l] + stbuf[64 + l] + stbuf[128 + l] + sb2[0];

        #pragma unroll
        for (int c = 0; c < 10; ++c) lg[c] += (double)cb2[c];
        double mx = lg[0]; int am2 = 0;
        #pragma unroll
        for (int c = 1; c < 10; ++c) {
            if (lg[c] > mx) { mx = lg[c]; am2 = c; }   // first-max == np.argmax
        }
        float tf[10]; float s = 0.f;
        #pragma unroll
        for (int c = 0; c < 10; ++c) { tf[c] = (float)(lg[c] - mx); s += __expf(tf[c]); }
        float ls = __logf(s);

        if (j > i) {
            const int p = i * 511 - (i * (i - 1)) / 2 + (j - i - 1);
            float* tp = out + TYPES_OFF + p * 10;
            #pragma unroll
            for (int c = 0; c < 10; ++c) tp[c] = tf[c] - ls;
            out[ARGMAX_OFF + p] = (float)am2;
            out[STRENGTH_OFF + p] = 1.0f / (1.0f + __expf(-st));
        }
    }
}

extern "C" void kernel_launch(void* const* d_in, const int* in_sizes, int n_in,
                              void* d_out, int out_size, void* d_ws, size_t ws_size,
                              hipStream_t stream) {
    const float* F   = (const float*)d_in[0];
    const float* cw1 = (const float*)d_in[1];
    const float* cb1 = (const float*)d_in[2];
    const float* cw2 = (const float*)d_in[3];
    const float* cb2 = (const float*)d_in[4];
    const float* sw1 = (const float*)d_in[5];
    const float* sb1 = (const float*)d_in[6];
    const float* sw2 = (const float*)d_in[7];
    const float* sb2 = (const float*)d_in[8];
    float* out = (float*)d_out;

    char* ws = (char*)d_ws;
    double* ca_d = (double*)(ws);
    double* cb_d = (double*)(ws + 2097152);
    float*  sa_f = (float*)(ws + 4194304);
    float*  sb_f = (float*)(ws + 4718592);
    double* cw2d = (double*)(ws + 5242880);

    hipLaunchKernelGGL(proj_kernel, dim3(404), dim3(256), 0, stream,
                       F, cw1, sw1, cb1, sb1, cw2,
                       ca_d, cb_d, sa_f, sb_f, cw2d);
    hipLaunchKernelGGL(pair_kernel, dim3(2080), dim3(256), 0, stream,
                       ca_d, cb_d, sa_f, sb_f, cw2d, cb2, sw2, sb2, out);
}